// Round 2
// baseline (1770.116 us; speedup 1.0000x reference)
//
#include <hip/hip_runtime.h>

typedef unsigned short u16;
typedef unsigned int u32;

#define HW 128

__device__ __forceinline__ float bf2f(u16 h) {
    u32 u = ((u32)h) << 16;
    return __uint_as_float(u);
}
__device__ __forceinline__ u16 f2bf(float f) {
    u32 u = __float_as_uint(f);
    u32 r = (u + 0x7FFFu + ((u >> 16) & 1u)) >> 16;
    return (u16)r;
}
__device__ __forceinline__ float lrelu_f(float v) {
    return v >= 0.f ? v : 0.1f * v;
}

// ---------------- weight transpose: [oc][ic][ky][kx] f32 -> [ic][ky][kx][oc] f32
template<int IC, int OC, int KS>
__global__ __launch_bounds__(256) void cvt_weights(const float* __restrict__ w, const float* __restrict__ b,
                                                   float* __restrict__ wdst, float* __restrict__ bdst) {
    int gid = blockIdx.x * 256 + threadIdx.x;
    constexpr int NW = OC * IC * KS * KS;
    if (gid < NW) {
        int kx = gid % KS;
        int t = gid / KS;
        int ky = t % KS; t /= KS;
        int ic = t % IC;
        int oc = t / IC;
        wdst[((ic * KS + ky) * KS + kx) * OC + oc] = w[gid];
    } else if (gid < NW + OC) {
        bdst[gid - NW] = b[gid - NW];
    }
}

// ---------------- upflow: transposed conv, lhs_dilation=2, pad=2, k=4, groups=2
__global__ __launch_bounds__(256) void upflow_kernel(const float* __restrict__ tflow, const float* __restrict__ wu,
                                                     float* __restrict__ flow) {
    int gid = blockIdx.x * 256 + threadIdx.x;   // 16*2*128*128 = 524288 exact
    int x = gid & 127;
    int y = (gid >> 7) & 127;
    int c = (gid >> 14) & 1;
    int b = gid >> 15;
    float acc = 0.f;
#pragma unroll
    for (int ky = 0; ky < 4; ++ky) {
        int u = y + ky - 2;
        if ((u & 1) || u < 0 || u > 126) continue;
        int iy = u >> 1;
#pragma unroll
        for (int kx = 0; kx < 4; ++kx) {
            int v = x + kx - 2;
            if ((v & 1) || v < 0 || v > 126) continue;
            int ix = v >> 1;
            acc += tflow[((b * 2 + c) * 64 + iy) * 64 + ix] *
                   wu[c * 16 + (3 - ky) * 4 + (3 - kx)];
        }
    }
    flow[gid] = acc;
}

// ---------------- backward warp into padded (pad=3) bf16 buffer (16,96,134,134)
__global__ __launch_bounds__(256) void warp_kernel(const float* __restrict__ second, const float* __restrict__ flow,
                                                   u16* __restrict__ feat2p) {
    int gid = blockIdx.x * 256 + threadIdx.x;
    if (gid >= 16 * 134 * 134) return;
    int b = gid / (134 * 134);
    int rem = gid - b * (134 * 134);
    int yp = rem / 134;
    int xp = rem - yp * 134;
    u16* outp = feat2p + (b * 96 * 134 + yp) * 134 + xp;  // channel stride 134*134
    if (yp < 3 || yp >= 131 || xp < 3 || xp >= 131) {
        for (int c = 0; c < 96; ++c) outp[c * 134 * 134] = 0;
        return;
    }
    int x = xp - 3, y = yp - 3;
    float fx = (float)x + 2.5f * flow[((b * 2 + 0) * HW + y) * HW + x];
    float fy = (float)y + 2.5f * flow[((b * 2 + 1) * HW + y) * HW + x];
    float x0f = floorf(fx), y0f = floorf(fy);
    int x0 = (int)x0f, y0 = (int)y0f;
    int x1 = x0 + 1, y1 = y0 + 1;
    float wx1 = fx - x0f, wx0 = (x0f + 1.f) - fx;
    float wy1 = fy - y0f, wy0 = (y0f + 1.f) - fy;
    float wA = wx0 * wy0, wB = wx1 * wy0, wC = wx0 * wy1, wD = wx1 * wy1;
    float vA = (x0 >= 0 && x0 <= 127 && y0 >= 0 && y0 <= 127) ? 1.f : 0.f;
    float vB = (x1 >= 0 && x1 <= 127 && y0 >= 0 && y0 <= 127) ? 1.f : 0.f;
    float vC = (x0 >= 0 && x0 <= 127 && y1 >= 0 && y1 <= 127) ? 1.f : 0.f;
    float vD = (x1 >= 0 && x1 <= 127 && y1 >= 0 && y1 <= 127) ? 1.f : 0.f;
    wA *= vA; wB *= vB; wC *= vC; wD *= vD;
    float ones = wA + wB + wC + wD;
    float maskf = (ones > 0.999f) ? 1.f : 0.f;
    wA *= maskf; wB *= maskf; wC *= maskf; wD *= maskf;
    int xc0 = min(max(x0, 0), 127), xc1 = min(max(x1, 0), 127);
    int yc0 = min(max(y0, 0), 127), yc1 = min(max(y1, 0), 127);
    int i00 = yc0 * HW + xc0, i01 = yc0 * HW + xc1;
    int i10 = yc1 * HW + xc0, i11 = yc1 * HW + xc1;
    const float* base = second + b * 96 * HW * HW;
    for (int c = 0; c < 96; ++c) {
        const float* pp = base + c * HW * HW;
        float v = wA * pp[i00] + wB * pp[i01] + wC * pp[i10] + wD * pp[i11];
        outp[c * 134 * 134] = f2bf(v);
    }
}

// ---------------- correlation (49 displacements) + lrelu into padded (pad=1) bf16 (16,49,130,130)
__global__ __launch_bounds__(256) void corr_kernel(const float* __restrict__ first, const u16* __restrict__ feat2p,
                                                   u16* __restrict__ corrp) {
    int gid = blockIdx.x * 256 + threadIdx.x;
    if (gid >= 16 * 130 * 130) return;
    int b = gid / (130 * 130);
    int rem = gid - b * (130 * 130);
    int yp = rem / 130;
    int xp = rem - yp * 130;
    u16* outp = corrp + (b * 49 * 130 + yp) * 130 + xp;  // d stride 130*130
    if (yp < 1 || yp >= 129 || xp < 1 || xp >= 129) {
        for (int d = 0; d < 49; ++d) outp[d * 16900] = 0;
        return;
    }
    int y = yp - 1, x = xp - 1;
    float acc[49];
#pragma unroll
    for (int d = 0; d < 49; ++d) acc[d] = 0.f;
    const float* fp0 = first + (b * 96 * HW + y) * HW + x;
    const u16* sp0 = feat2p + (b * 96 * 134 + y) * 134 + x;  // +dy,+dx covers shift (pad 3 built in)
    for (int c = 0; c < 96; ++c) {
        float f = fp0[c * HW * HW];
        const u16* sp = sp0 + c * 134 * 134;
#pragma unroll
        for (int dy = 0; dy < 7; ++dy)
#pragma unroll
            for (int dx = 0; dx < 7; ++dx)
                acc[dy * 7 + dx] += f * bf2f(sp[dy * 134 + dx]);
    }
#pragma unroll
    for (int d = 0; d < 49; ++d) {
        float v = acc[d] * (1.f / 96.f);
        outp[d * 16900] = f2bf(lrelu_f(v));
    }
}

// ---------------- direct conv. input padded by KS/2 (bf16), weights [ic][ky][kx][oc] f32 (uniform -> s_load)
template<int IC, int OC, int KS, int OCPT, int OUTPAD, bool LRELU, bool FINAL>
__global__ __launch_bounds__(256) void conv_kernel(const u16* __restrict__ in, const float* __restrict__ w,
                                                   const float* __restrict__ bias, void* __restrict__ outv,
                                                   const float* __restrict__ flow) {
    constexpr int INPAD = KS / 2;
    constexpr int Wi = HW + 2 * INPAD;
    constexpr int Wo = HW + 2 * OUTPAD;
    constexpr int OCG = OC / OCPT;
    int tid = threadIdx.x;
    int x = tid & 127;
    int ry = tid >> 7;  // 0..1
    int blk = blockIdx.x;
    int rowblk = blk & 63;
    int t = blk >> 6;
    int ocg = t % OCG;
    int b = t / OCG;
    int y = rowblk * 2 + ry;
    int oc0 = ocg * OCPT;

    float acc[OCPT];
#pragma unroll
    for (int j = 0; j < OCPT; ++j) acc[j] = bias[oc0 + j];

    const u16* ip = in + ((b * IC) * Wi + y) * Wi + x;
    for (int ic = 0; ic < IC; ++ic) {
        const u16* cp = ip + ic * Wi * Wi;
#pragma unroll
        for (int ky = 0; ky < KS; ++ky) {
            const u16* rp = cp + ky * Wi;
#pragma unroll
            for (int kx = 0; kx < KS; ++kx) {
                float v = bf2f(rp[kx]);
                const float* wp = w + ((ic * KS + ky) * KS + kx) * OC + oc0;
#pragma unroll
                for (int j = 0; j < OCPT; ++j) acc[j] += v * wp[j];
            }
        }
    }

    if constexpr (FINAL) {
        float* out = (float*)outv;
#pragma unroll
        for (int j = 0; j < OCPT; ++j) {
            int oi = ((b * OC + oc0 + j) * HW + y) * HW + x;
            out[oi] = acc[j] + flow[oi];
        }
    } else {
        u16* out = (u16*)outv;
#pragma unroll
        for (int j = 0; j < OCPT; ++j) {
            float v = LRELU ? lrelu_f(acc[j]) : acc[j];
            out[((b * OC + oc0 + j) * Wo + (y + OUTPAD)) * Wo + (x + OUTPAD)] = f2bf(v);
        }
    }
}

// ---------------- launch
extern "C" void kernel_launch(void* const* d_in, const int* in_sizes, int n_in,
                              void* d_out, int out_size, void* d_ws, size_t ws_size,
                              hipStream_t stream) {
    const float* ffirst  = (const float*)d_in[2];
    const float* fsecond = (const float*)d_in[3];
    const float* tflow   = (const float*)d_in[4];
    const float* wu      = (const float*)d_in[5];
    const float* w1 = (const float*)d_in[6];
    const float* b1 = (const float*)d_in[7];
    const float* w2 = (const float*)d_in[8];
    const float* b2 = (const float*)d_in[9];
    const float* w3 = (const float*)d_in[10];
    const float* b3 = (const float*)d_in[11];
    const float* w4 = (const float*)d_in[12];
    const float* b4 = (const float*)d_in[13];
    float* out = (float*)d_out;
    char* ws = (char*)d_ws;

    // weight region (f32): w1t 56448 | b1 128 | w2t 73728 | b2 64 | w3t 18432 | b3 32 | w4t 1600 | b4 2
    float* wbuf = (float*)(ws);
    float* w1t = wbuf + 0;
    float* b1t = wbuf + 56448;
    float* w2t = wbuf + 56576;
    float* b2t = wbuf + 130304;
    float* w3t = wbuf + 130368;
    float* b3t = wbuf + 148800;
    float* w4t = wbuf + 148832;
    float* b4t = wbuf + 150432;

    float* flow = (float*)(ws + 602112);                 // 524288 f32, ends 2699264
    u16* regA = (u16*)(ws + 2699264);                    // feat2p (55.2MB) -> x1p (69.2MB) -> x3p (17.8MB)
    u16* regB = (u16*)(ws + 71921664);                   // corrp (26.5MB) -> x2p (34.6MB); end 106532864

    // 1) weights
    cvt_weights<49, 128, 3><<<222, 256, 0, stream>>>(w1, b1, w1t, b1t);
    cvt_weights<128, 64, 3><<<289, 256, 0, stream>>>(w2, b2, w2t, b2t);
    cvt_weights<64, 32, 3><<<73, 256, 0, stream>>>(w3, b3, w3t, b3t);
    cvt_weights<32, 2, 5><<<8, 256, 0, stream>>>(w4, b4, w4t, b4t);

    // 2) upflow -> flow (f32)
    upflow_kernel<<<2048, 256, 0, stream>>>(tflow, wu, flow);

    // 3) warp features -> feat2p (pad 3, bf16)
    hipMemsetAsync(regA, 0, 55160832, stream);
    warp_kernel<<<1123, 256, 0, stream>>>(fsecond, flow, regA);

    // 4) correlation + lrelu -> corrp (pad 1, bf16)
    hipMemsetAsync(regB, 0, 26499200, stream);
    corr_kernel<<<1057, 256, 0, stream>>>(ffirst, regA, regB);

    // 5) conv1 49->128 + lrelu -> x1p (pad 1), overwrites feat2p region
    hipMemsetAsync(regA, 0, 69222400, stream);
    conv_kernel<49, 128, 3, 8, 1, true, false><<<16384, 256, 0, stream>>>(regB, w1t, b1t, regA, nullptr);

    // 6) conv2 128->64 + lrelu -> x2p (pad 1), overwrites corrp region
    hipMemsetAsync(regB, 0, 34611200, stream);
    conv_kernel<128, 64, 3, 8, 1, true, false><<<8192, 256, 0, stream>>>(regA, w2t, b2t, regB, nullptr);

    // 7) conv3 64->32 + lrelu -> x3p (pad 2, conv4 is 5x5), overwrites x1p region (x1 dead after conv2)
    hipMemsetAsync(regA, 0, 17842176, stream);
    conv_kernel<64, 32, 3, 8, 2, true, false><<<4096, 256, 0, stream>>>(regB, w3t, b3t, regA, nullptr);

    // 8) conv4 32->2 (5x5) + flow add -> d_out (f32)
    conv_kernel<32, 2, 5, 2, 0, false, true><<<1024, 256, 0, stream>>>(regA, w4t, b4t, out, flow);
}

// Round 3
// 902.117 us; speedup vs baseline: 1.9622x; 1.9622x over previous
//
#include <hip/hip_runtime.h>

typedef unsigned short u16;
typedef unsigned int u32;
typedef short short8 __attribute__((ext_vector_type(8)));
typedef float f32x4 __attribute__((ext_vector_type(4)));

#define HW 128

__device__ __forceinline__ float bf2f(u16 h) {
    u32 u = ((u32)h) << 16;
    return __uint_as_float(u);
}
__device__ __forceinline__ u16 f2bf(float f) {
    u32 u = __float_as_uint(f);
    u32 r = (u + 0x7FFFu + ((u >> 16) & 1u)) >> 16;
    return (u16)r;
}
__device__ __forceinline__ float lrelu_f(float v) {
    return v >= 0.f ? v : 0.1f * v;
}

// ---------------- weight pack for MFMA convs: [oc][ic][3][3] f32 -> [tap][ch][quad][oc][j8] bf16
// k = ch*32 + quad*8 + j indexes ic (zero-padded ICR..ICP)
template<int ICR, int ICP, int OC>
__global__ __launch_bounds__(256) void pack_w(const float* __restrict__ w, u16* __restrict__ dst) {
    constexpr int NCH = ICP / 32;
    constexpr int NTOT = 9 * NCH * 4 * OC * 8;
    int gid = blockIdx.x * 256 + threadIdx.x;
    if (gid >= NTOT) return;
    int j = gid & 7;
    int t = gid >> 3;
    int oc = t % OC; t /= OC;
    int quad = t & 3; t >>= 2;
    int ch = t % NCH;
    int tap = t / NCH;
    int ic = ch * 32 + quad * 8 + j;
    int ky = tap / 3, kx = tap % 3;
    float v = (ic < ICR) ? w[((oc * ICR + ic) * 3 + ky) * 3 + kx] : 0.f;
    dst[gid] = f2bf(v);
}

// ---------------- conv4 weight pack: [2][32][5][5] f32 -> [tap(25)][oc(2)][ic(32)] f32
__global__ __launch_bounds__(256) void pack_w4(const float* __restrict__ w, float* __restrict__ dst) {
    int gid = blockIdx.x * 256 + threadIdx.x;
    if (gid >= 1600) return;
    int ic = gid & 31;
    int t = gid >> 5;
    int oc = t & 1;
    int tap = t >> 1;
    dst[(tap * 2 + oc) * 32 + ic] = w[(oc * 32 + ic) * 25 + tap];
}

// ---------------- upflow: transposed conv, lhs_dilation=2, pad=2, k=4, groups=2
__global__ __launch_bounds__(256) void upflow_kernel(const float* __restrict__ tflow, const float* __restrict__ wu,
                                                     float* __restrict__ flow) {
    int gid = blockIdx.x * 256 + threadIdx.x;   // 524288 exact
    int x = gid & 127;
    int y = (gid >> 7) & 127;
    int c = (gid >> 14) & 1;
    int b = gid >> 15;
    float acc = 0.f;
#pragma unroll
    for (int ky = 0; ky < 4; ++ky) {
        int u = y + ky - 2;
        if ((u & 1) || u < 0 || u > 126) continue;
        int iy = u >> 1;
#pragma unroll
        for (int kx = 0; kx < 4; ++kx) {
            int v = x + kx - 2;
            if ((v & 1) || v < 0 || v > 126) continue;
            int ix = v >> 1;
            acc += tflow[((b * 2 + c) * 64 + iy) * 64 + ix] *
                   wu[c * 16 + (3 - ky) * 4 + (3 - kx)];
        }
    }
    flow[gid] = acc;
}

// ---------------- backward warp into padded (pad=3) NCHW bf16 (16,96,134,134)
__global__ __launch_bounds__(256) void warp_kernel(const float* __restrict__ second, const float* __restrict__ flow,
                                                   u16* __restrict__ feat2p) {
    int gid = blockIdx.x * 256 + threadIdx.x;   // 16*128*128 interior only (halo pre-zeroed)
    if (gid >= 16 * HW * HW) return;
    int x = gid & 127;
    int y = (gid >> 7) & 127;
    int b = gid >> 14;
    float fx = (float)x + 2.5f * flow[((b * 2 + 0) * HW + y) * HW + x];
    float fy = (float)y + 2.5f * flow[((b * 2 + 1) * HW + y) * HW + x];
    float x0f = floorf(fx), y0f = floorf(fy);
    int x0 = (int)x0f, y0 = (int)y0f;
    int x1 = x0 + 1, y1 = y0 + 1;
    float wx1 = fx - x0f, wx0 = (x0f + 1.f) - fx;
    float wy1 = fy - y0f, wy0 = (y0f + 1.f) - fy;
    float wA = wx0 * wy0, wB = wx1 * wy0, wC = wx0 * wy1, wD = wx1 * wy1;
    float vA = (x0 >= 0 && x0 <= 127 && y0 >= 0 && y0 <= 127) ? 1.f : 0.f;
    float vB = (x1 >= 0 && x1 <= 127 && y0 >= 0 && y0 <= 127) ? 1.f : 0.f;
    float vC = (x0 >= 0 && x0 <= 127 && y1 >= 0 && y1 <= 127) ? 1.f : 0.f;
    float vD = (x1 >= 0 && x1 <= 127 && y1 >= 0 && y1 <= 127) ? 1.f : 0.f;
    wA *= vA; wB *= vB; wC *= vC; wD *= vD;
    float ones = wA + wB + wC + wD;
    float maskf = (ones > 0.999f) ? 1.f : 0.f;
    wA *= maskf; wB *= maskf; wC *= maskf; wD *= maskf;
    int xc0 = min(max(x0, 0), 127), xc1 = min(max(x1, 0), 127);
    int yc0 = min(max(y0, 0), 127), yc1 = min(max(y1, 0), 127);
    int i00 = yc0 * HW + xc0, i01 = yc0 * HW + xc1;
    int i10 = yc1 * HW + xc0, i11 = yc1 * HW + xc1;
    const float* base = second + (size_t)b * 96 * HW * HW;
    u16* outp = feat2p + ((size_t)(b * 96) * 134 + (y + 3)) * 134 + (x + 3);
    for (int c = 0; c < 96; ++c) {
        const float* pp = base + c * HW * HW;
        float v = wA * pp[i00] + wB * pp[i01] + wC * pp[i10] + wD * pp[i11];
        outp[c * 134 * 134] = f2bf(v);
    }
}

// ---------------- correlation + lrelu -> NHWC (16,130,130,64) bf16, d padded 49->64 (halo pre-zeroed)
__global__ __launch_bounds__(256) void corr_kernel(const float* __restrict__ first, const u16* __restrict__ feat2p,
                                                   u16* __restrict__ corrp) {
    int gid = blockIdx.x * 256 + threadIdx.x;   // 16*128*128
    int x = gid & 127;
    int y = (gid >> 7) & 127;
    int b = gid >> 14;
    float acc[49];
#pragma unroll
    for (int d = 0; d < 49; ++d) acc[d] = 0.f;
    const float* fp0 = first + ((size_t)(b * 96) * HW + y) * HW + x;
    const u16* sp0 = feat2p + ((size_t)(b * 96) * 134 + y) * 134 + x;  // pad-3 built in
    for (int c = 0; c < 96; ++c) {
        float f = fp0[c * HW * HW];
        const u16* sp = sp0 + c * 134 * 134;
#pragma unroll
        for (int dy = 0; dy < 7; ++dy)
#pragma unroll
            for (int dx = 0; dx < 7; ++dx)
                acc[dy * 7 + dx] += f * bf2f(sp[dy * 134 + dx]);
    }
    u16* op = corrp + (((size_t)(b * 130) + y + 1) * 130 + (x + 1)) * 64;
#pragma unroll
    for (int d = 0; d < 49; ++d)
        op[d] = f2bf(lrelu_f(acc[d] * (1.f / 96.f)));
}

// ---------------- MFMA conv 3x3: NHWC pad-1 in (130x130xICP) -> NHWC pad-PADOUT out, + bias + lrelu
// wave: 64 pixels (half row) x OCB ocs. block: 4 waves = 2 rows.
template<int ICP, int OC, int OCB, int PADOUT>
__global__ __launch_bounds__(256) void conv_mfma(const u16* __restrict__ in, const u16* __restrict__ wp,
                                                 const float* __restrict__ bias, u16* __restrict__ out) {
    constexpr int NCH = ICP / 32;
    constexpr int NOCT = OCB / 16;
    constexpr int OCG = OC / OCB;
    constexpr int Wi = 130;
    constexpr int Wo = 128 + 2 * PADOUT;
    int tid = threadIdx.x;
    int wave = tid >> 6, lane = tid & 63;
    int quad = lane >> 4, l16 = lane & 15;
    int rowpair = blockIdx.x & 63;
    int t = blockIdx.x >> 6;
    int ocg = t % OCG;
    int b = t / OCG;
    int row = rowpair * 2 + (wave >> 1);
    int px0 = (wave & 1) * 64;

    f32x4 acc[4][NOCT];
#pragma unroll
    for (int mt = 0; mt < 4; ++mt)
#pragma unroll
        for (int ot = 0; ot < NOCT; ++ot)
            acc[mt][ot] = (f32x4){0.f, 0.f, 0.f, 0.f};

#pragma unroll
    for (int ky = 0; ky < 3; ++ky) {
#pragma unroll
        for (int kx = 0; kx < 3; ++kx) {
#pragma unroll
            for (int ch = 0; ch < NCH; ++ch) {
                const u16* aptr = in + ((size_t)(b * Wi + row + ky) * Wi + px0 + kx + l16) * ICP + ch * 32 + quad * 8;
                short8 afr[4];
#pragma unroll
                for (int mt = 0; mt < 4; ++mt)
                    afr[mt] = *(const short8*)(aptr + mt * 16 * ICP);
                const u16* bptr = wp + ((((size_t)(ky * 3 + kx) * NCH + ch) * 4 + quad) * OC + ocg * OCB + l16) * 8;
                short8 bfr[NOCT];
#pragma unroll
                for (int ot = 0; ot < NOCT; ++ot)
                    bfr[ot] = *(const short8*)(bptr + ot * 16 * 8);
#pragma unroll
                for (int mt = 0; mt < 4; ++mt)
#pragma unroll
                    for (int ot = 0; ot < NOCT; ++ot)
                        acc[mt][ot] = __builtin_amdgcn_mfma_f32_16x16x32_bf16(afr[mt], bfr[ot], acc[mt][ot], 0, 0, 0);
            }
        }
    }

    float bv[NOCT];
#pragma unroll
    for (int ot = 0; ot < NOCT; ++ot) bv[ot] = bias[ocg * OCB + ot * 16 + l16];

#pragma unroll
    for (int mt = 0; mt < 4; ++mt) {
#pragma unroll
        for (int ot = 0; ot < NOCT; ++ot) {
#pragma unroll
            for (int r = 0; r < 4; ++r) {
                int px = px0 + mt * 16 + quad * 4 + r;
                float v = lrelu_f(acc[mt][ot][r] + bv[ot]);
                out[((size_t)(b * Wo + row + PADOUT) * Wo + px + PADOUT) * OC + ocg * OCB + ot * 16 + l16] = f2bf(v);
            }
        }
    }
}

// ---------------- conv4: 5x5, 32->2, NHWC pad-2 in (132x132x32), + flow add -> NCHW f32 out
__global__ __launch_bounds__(256) void conv4_kernel(const u16* __restrict__ in, const float* __restrict__ w4p,
                                                    const float* __restrict__ b4, const float* __restrict__ flow,
                                                    float* __restrict__ out) {
    int gid = blockIdx.x * 256 + threadIdx.x;   // 16*128*128
    int x = gid & 127;
    int y = (gid >> 7) & 127;
    int b = gid >> 14;
    float acc0 = b4[0], acc1 = b4[1];
#pragma unroll
    for (int ky = 0; ky < 5; ++ky) {
#pragma unroll
        for (int kx = 0; kx < 5; ++kx) {
            const u16* p = in + ((size_t)(b * 132 + y + ky) * 132 + x + kx) * 32;
            const float* wb = w4p + (ky * 5 + kx) * 64;
#pragma unroll
            for (int g = 0; g < 4; ++g) {
                short8 vv = *(const short8*)(p + g * 8);
#pragma unroll
                for (int j = 0; j < 8; ++j) {
                    float v = bf2f((u16)vv[j]);
                    acc0 += v * wb[g * 8 + j];
                    acc1 += v * wb[32 + g * 8 + j];
                }
            }
        }
    }
    int o0 = ((b * 2 + 0) * HW + y) * HW + x;
    int o1 = o0 + HW * HW;
    out[o0] = acc0 + flow[o0];
    out[o1] = acc1 + flow[o1];
}

// ---------------- launch
extern "C" void kernel_launch(void* const* d_in, const int* in_sizes, int n_in,
                              void* d_out, int out_size, void* d_ws, size_t ws_size,
                              hipStream_t stream) {
    const float* ffirst  = (const float*)d_in[2];
    const float* fsecond = (const float*)d_in[3];
    const float* tflow   = (const float*)d_in[4];
    const float* wu      = (const float*)d_in[5];
    const float* w1 = (const float*)d_in[6];
    const float* b1 = (const float*)d_in[7];
    const float* w2 = (const float*)d_in[8];
    const float* b2 = (const float*)d_in[9];
    const float* w3 = (const float*)d_in[10];
    const float* b3 = (const float*)d_in[11];
    const float* w4 = (const float*)d_in[12];
    const float* b4 = (const float*)d_in[13];
    float* out = (float*)d_out;
    char* ws = (char*)d_ws;

    // packed weights: w1p 147456B | w2p 147456B | w3p 36864B | w4p 6400B (f32)
    u16* w1p = (u16*)(ws + 0);
    u16* w2p = (u16*)(ws + 147456);
    u16* w3p = (u16*)(ws + 294912);
    float* w4p = (float*)(ws + 331776);

    float* flow = (float*)(ws + 602112);   // 524288 f32, ends 2699264
    u16* regA = (u16*)(ws + 2699264);      // feat2p 55.2MB -> x1p 69.2MB -> x3p 17.8MB
    u16* regB = (u16*)(ws + 71921664);     // corr 34.6MB -> x2p 34.6MB; end 106532864

    // 1) weight packing
    pack_w<49, 64, 128><<<288, 256, 0, stream>>>(w1, w1p);
    pack_w<128, 128, 64><<<288, 256, 0, stream>>>(w2, w2p);
    pack_w<64, 64, 32><<<72, 256, 0, stream>>>(w3, w3p);
    pack_w4<<<7, 256, 0, stream>>>(w4, w4p);

    // 2) upflow -> flow (f32 NCHW)
    upflow_kernel<<<2048, 256, 0, stream>>>(tflow, wu, flow);

    // 3) warp -> feat2p (NCHW pad3 bf16)
    hipMemsetAsync(regA, 0, 55160832, stream);
    warp_kernel<<<1024, 256, 0, stream>>>(fsecond, flow, regA);

    // 4) correlation + lrelu -> NHWC (130,130,64) bf16
    hipMemsetAsync(regB, 0, 34611200, stream);
    corr_kernel<<<1024, 256, 0, stream>>>(ffirst, regA, regB);

    // 5) conv1 64->128 MFMA -> x1p NHWC pad1
    hipMemsetAsync(regA, 0, 69222400, stream);
    conv_mfma<64, 128, 64, 1><<<2048, 256, 0, stream>>>(regB, w1p, b1, regA);

    // 6) conv2 128->64 MFMA -> x2p NHWC pad1
    hipMemsetAsync(regB, 0, 34611200, stream);
    conv_mfma<128, 64, 64, 1><<<1024, 256, 0, stream>>>(regA, w2p, b2, regB);

    // 7) conv3 64->32 MFMA -> x3p NHWC pad2
    hipMemsetAsync(regA, 0, 17842176, stream);
    conv_mfma<64, 32, 32, 2><<<1024, 256, 0, stream>>>(regB, w3p, b3, regA);

    // 8) conv4 5x5 32->2 + flow add -> d_out (f32 NCHW)
    conv4_kernel<<<1024, 256, 0, stream>>>(regA, w4p, b4, flow, out);
}

// Round 4
// 764.540 us; speedup vs baseline: 2.3153x; 1.1799x over previous
//
#include <hip/hip_runtime.h>

typedef unsigned short u16;
typedef unsigned int u32;
typedef short short8 __attribute__((ext_vector_type(8)));
typedef float f32x4 __attribute__((ext_vector_type(4)));

#define HW 128

__device__ __forceinline__ float bf2f(u16 h) {
    u32 u = ((u32)h) << 16;
    return __uint_as_float(u);
}
__device__ __forceinline__ u16 f2bf(float f) {
    u32 u = __float_as_uint(f);
    u32 r = (u + 0x7FFFu + ((u >> 16) & 1u)) >> 16;
    return (u16)r;
}
__device__ __forceinline__ float lrelu_f(float v) {
    return v >= 0.f ? v : 0.1f * v;
}

// ---------------- weight pack for MFMA convs: [oc][ic][3][3] f32 -> [tap][ch][quad][oc][j8] bf16
template<int ICR, int ICP, int OC>
__global__ __launch_bounds__(256) void pack_w(const float* __restrict__ w, u16* __restrict__ dst) {
    constexpr int NCH = ICP / 32;
    constexpr int NTOT = 9 * NCH * 4 * OC * 8;
    int gid = blockIdx.x * 256 + threadIdx.x;
    if (gid >= NTOT) return;
    int j = gid & 7;
    int t = gid >> 3;
    int oc = t % OC; t /= OC;
    int quad = t & 3; t >>= 2;
    int ch = t % NCH;
    int tap = t / NCH;
    int ic = ch * 32 + quad * 8 + j;
    int ky = tap / 3, kx = tap % 3;
    float v = (ic < ICR) ? w[((oc * ICR + ic) * 3 + ky) * 3 + kx] : 0.f;
    dst[gid] = f2bf(v);
}

// ---------------- conv4 weight pack: [2][32][5][5] f32 -> [tap(25)][oc(2)][ic(32)] f32
__global__ __launch_bounds__(256) void pack_w4(const float* __restrict__ w, float* __restrict__ dst) {
    int gid = blockIdx.x * 256 + threadIdx.x;
    if (gid >= 1600) return;
    int ic = gid & 31;
    int t = gid >> 5;
    int oc = t & 1;
    int tap = t >> 1;
    dst[(tap * 2 + oc) * 32 + ic] = w[(oc * 32 + ic) * 25 + tap];
}

// ---------------- upflow: transposed conv, lhs_dilation=2, pad=2, k=4, groups=2
__global__ __launch_bounds__(256) void upflow_kernel(const float* __restrict__ tflow, const float* __restrict__ wu,
                                                     float* __restrict__ flow) {
    int gid = blockIdx.x * 256 + threadIdx.x;   // 524288 exact
    int x = gid & 127;
    int y = (gid >> 7) & 127;
    int c = (gid >> 14) & 1;
    int b = gid >> 15;
    float acc = 0.f;
#pragma unroll
    for (int ky = 0; ky < 4; ++ky) {
        int u = y + ky - 2;
        if ((u & 1) || u < 0 || u > 126) continue;
        int iy = u >> 1;
#pragma unroll
        for (int kx = 0; kx < 4; ++kx) {
            int v = x + kx - 2;
            if ((v & 1) || v < 0 || v > 126) continue;
            int ix = v >> 1;
            acc += tflow[((b * 2 + c) * 64 + iy) * 64 + ix] *
                   wu[c * 16 + (3 - ky) * 4 + (3 - kx)];
        }
    }
    flow[gid] = acc;
}

// ---------------- backward warp -> NHWC bf16 feat2 (16,134,144,96), pad 3 built in, x-pad to 144
__global__ __launch_bounds__(256) void warp_kernel(const float* __restrict__ second, const float* __restrict__ flow,
                                                   u16* __restrict__ feat2) {
    int gid = blockIdx.x * 256 + threadIdx.x;   // 16*128*128 interior only (halo pre-zeroed)
    int x = gid & 127;
    int y = (gid >> 7) & 127;
    int b = gid >> 14;
    float fx = (float)x + 2.5f * flow[((b * 2 + 0) * HW + y) * HW + x];
    float fy = (float)y + 2.5f * flow[((b * 2 + 1) * HW + y) * HW + x];
    float x0f = floorf(fx), y0f = floorf(fy);
    int x0 = (int)x0f, y0 = (int)y0f;
    int x1 = x0 + 1, y1 = y0 + 1;
    float wx1 = fx - x0f, wx0 = (x0f + 1.f) - fx;
    float wy1 = fy - y0f, wy0 = (y0f + 1.f) - fy;
    float wA = wx0 * wy0, wB = wx1 * wy0, wC = wx0 * wy1, wD = wx1 * wy1;
    float vA = (x0 >= 0 && x0 <= 127 && y0 >= 0 && y0 <= 127) ? 1.f : 0.f;
    float vB = (x1 >= 0 && x1 <= 127 && y0 >= 0 && y0 <= 127) ? 1.f : 0.f;
    float vC = (x0 >= 0 && x0 <= 127 && y1 >= 0 && y1 <= 127) ? 1.f : 0.f;
    float vD = (x1 >= 0 && x1 <= 127 && y1 >= 0 && y1 <= 127) ? 1.f : 0.f;
    wA *= vA; wB *= vB; wC *= vC; wD *= vD;
    float ones = wA + wB + wC + wD;
    float maskf = (ones > 0.999f) ? 1.f : 0.f;
    wA *= maskf; wB *= maskf; wC *= maskf; wD *= maskf;
    int xc0 = min(max(x0, 0), 127), xc1 = min(max(x1, 0), 127);
    int yc0 = min(max(y0, 0), 127), yc1 = min(max(y1, 0), 127);
    int i00 = yc0 * HW + xc0, i01 = yc0 * HW + xc1;
    int i10 = yc1 * HW + xc0, i11 = yc1 * HW + xc1;
    const float* base = second + (size_t)b * 96 * HW * HW;
    u16* outp = feat2 + (((size_t)(b * 134) + y + 3) * 144 + (x + 3)) * 96;
    for (int cg = 0; cg < 12; ++cg) {
        short8 o;
#pragma unroll
        for (int j = 0; j < 8; ++j) {
            const float* pp = base + (size_t)(cg * 8 + j) * (HW * HW);
            float v = wA * pp[i00] + wB * pp[i01] + wC * pp[i10] + wD * pp[i11];
            o[j] = (short)f2bf(v);
        }
        *(short8*)(outp + cg * 8) = o;
    }
}

// ---------------- correlation as banded MFMA GEMM -> NHWC (16,130,130,64) bf16 corr, + /96 + lrelu
// wave: 16 pixels (m) x [2 N-tiles x 7 dy] accs; A from fp32 NCHW first, B from NHWC bf16 feat2
__global__ __launch_bounds__(256) void corr_mfma(const float* __restrict__ first, const u16* __restrict__ feat2,
                                                 u16* __restrict__ corrp) {
    int tid = threadIdx.x;
    int wave = tid >> 6, lane = tid & 63;
    int quad = lane >> 4, l16 = lane & 15;
    int blk = blockIdx.x;            // 16 * 128 * 2 = 4096
    int half = blk & 1;
    int y = (blk >> 1) & 127;
    int b = blk >> 8;
    int x0 = (half * 4 + wave) * 16;

    // A fragments: lane m=l16 -> pixel x0+l16, k = ch*32 + quad*8 + j (channel), from fp32 NCHW
    short8 afr[3];
    const float* fbase = first + ((size_t)(b * 96) * HW + y) * HW + x0 + l16;
#pragma unroll
    for (int ch = 0; ch < 3; ++ch) {
        short8 a;
#pragma unroll
        for (int j = 0; j < 8; ++j)
            a[j] = (short)f2bf(fbase[(size_t)(ch * 32 + quad * 8 + j) * (HW * HW)]);
        afr[ch] = a;
    }

    f32x4 acc[7][2];
#pragma unroll
    for (int dy = 0; dy < 7; ++dy) {
        acc[dy][0] = (f32x4){0.f, 0.f, 0.f, 0.f};
        acc[dy][1] = (f32x4){0.f, 0.f, 0.f, 0.f};
    }

    const u16* sb = feat2 + ((size_t)(b * 134) + y) * (144 * 96);
#pragma unroll
    for (int dy = 0; dy < 7; ++dy) {
        const u16* rp = sb + (size_t)dy * (144 * 96);
#pragma unroll
        for (int ch = 0; ch < 3; ++ch) {
            short8 b0 = *(const short8*)(rp + (x0 + l16) * 96 + ch * 32 + quad * 8);
            short8 b1 = *(const short8*)(rp + (x0 + 16 + l16) * 96 + ch * 32 + quad * 8);
            acc[dy][0] = __builtin_amdgcn_mfma_f32_16x16x32_bf16(afr[ch], b0, acc[dy][0], 0, 0, 0);
            acc[dy][1] = __builtin_amdgcn_mfma_f32_16x16x32_bf16(afr[ch], b1, acc[dy][1], 0, 0, 0);
        }
    }

    // band extract: lane holds col n=l16 (within tile), rows m=quad*4+r; dx = nt*16+l16-m
    u16* op = corrp + ((size_t)(b * 130) + y + 1) * (130 * 64);
#pragma unroll
    for (int dy = 0; dy < 7; ++dy)
#pragma unroll
        for (int nt = 0; nt < 2; ++nt)
#pragma unroll
            for (int r = 0; r < 4; ++r) {
                int m = quad * 4 + r;
                int dx = nt * 16 + l16 - m;
                if (dx >= 0 && dx < 7) {
                    float v = lrelu_f(acc[dy][nt][r] * (1.f / 96.f));
                    op[(size_t)(x0 + m + 1) * 64 + dy * 7 + dx] = f2bf(v);
                }
            }
}

// ---------------- MFMA conv 3x3: NHWC pad-1 in (130x130xICP) -> NHWC pad-PADOUT out, + bias + lrelu
template<int ICP, int OC, int OCB, int PADOUT>
__global__ __launch_bounds__(256) void conv_mfma(const u16* __restrict__ in, const u16* __restrict__ wp,
                                                 const float* __restrict__ bias, u16* __restrict__ out) {
    constexpr int NCH = ICP / 32;
    constexpr int NOCT = OCB / 16;
    constexpr int OCG = OC / OCB;
    constexpr int Wi = 130;
    constexpr int Wo = 128 + 2 * PADOUT;
    int tid = threadIdx.x;
    int wave = tid >> 6, lane = tid & 63;
    int quad = lane >> 4, l16 = lane & 15;
    int rowpair = blockIdx.x & 63;
    int t = blockIdx.x >> 6;
    int ocg = t % OCG;
    int b = t / OCG;
    int row = rowpair * 2 + (wave >> 1);
    int px0 = (wave & 1) * 64;

    f32x4 acc[4][NOCT];
#pragma unroll
    for (int mt = 0; mt < 4; ++mt)
#pragma unroll
        for (int ot = 0; ot < NOCT; ++ot)
            acc[mt][ot] = (f32x4){0.f, 0.f, 0.f, 0.f};

#pragma unroll
    for (int ky = 0; ky < 3; ++ky) {
#pragma unroll
        for (int kx = 0; kx < 3; ++kx) {
#pragma unroll
            for (int ch = 0; ch < NCH; ++ch) {
                const u16* aptr = in + ((size_t)(b * Wi + row + ky) * Wi + px0 + kx + l16) * ICP + ch * 32 + quad * 8;
                short8 afr[4];
#pragma unroll
                for (int mt = 0; mt < 4; ++mt)
                    afr[mt] = *(const short8*)(aptr + mt * 16 * ICP);
                const u16* bptr = wp + ((((size_t)(ky * 3 + kx) * NCH + ch) * 4 + quad) * OC + ocg * OCB + l16) * 8;
                short8 bfr[NOCT];
#pragma unroll
                for (int ot = 0; ot < NOCT; ++ot)
                    bfr[ot] = *(const short8*)(bptr + ot * 16 * 8);
#pragma unroll
                for (int mt = 0; mt < 4; ++mt)
#pragma unroll
                    for (int ot = 0; ot < NOCT; ++ot)
                        acc[mt][ot] = __builtin_amdgcn_mfma_f32_16x16x32_bf16(afr[mt], bfr[ot], acc[mt][ot], 0, 0, 0);
            }
        }
    }

    float bv[NOCT];
#pragma unroll
    for (int ot = 0; ot < NOCT; ++ot) bv[ot] = bias[ocg * OCB + ot * 16 + l16];

#pragma unroll
    for (int mt = 0; mt < 4; ++mt) {
#pragma unroll
        for (int ot = 0; ot < NOCT; ++ot) {
#pragma unroll
            for (int r = 0; r < 4; ++r) {
                int px = px0 + mt * 16 + quad * 4 + r;
                float v = lrelu_f(acc[mt][ot][r] + bv[ot]);
                out[((size_t)(b * Wo + row + PADOUT) * Wo + px + PADOUT) * OC + ocg * OCB + ot * 16 + l16] = f2bf(v);
            }
        }
    }
}

// ---------------- conv4: 5x5, 32->2, NHWC pad-2 in (132x132x32), + flow add -> NCHW f32 out
__global__ __launch_bounds__(256) void conv4_kernel(const u16* __restrict__ in, const float* __restrict__ w4p,
                                                    const float* __restrict__ b4, const float* __restrict__ flow,
                                                    float* __restrict__ out) {
    int gid = blockIdx.x * 256 + threadIdx.x;   // 16*128*128
    int x = gid & 127;
    int y = (gid >> 7) & 127;
    int b = gid >> 14;
    float acc0 = b4[0], acc1 = b4[1];
#pragma unroll
    for (int ky = 0; ky < 5; ++ky) {
#pragma unroll
        for (int kx = 0; kx < 5; ++kx) {
            const u16* p = in + ((size_t)(b * 132 + y + ky) * 132 + x + kx) * 32;
            const float* wb = w4p + (ky * 5 + kx) * 64;
#pragma unroll
            for (int g = 0; g < 4; ++g) {
                short8 vv = *(const short8*)(p + g * 8);
#pragma unroll
                for (int j = 0; j < 8; ++j) {
                    float v = bf2f((u16)vv[j]);
                    acc0 += v * wb[g * 8 + j];
                    acc1 += v * wb[32 + g * 8 + j];
                }
            }
        }
    }
    int o0 = ((b * 2 + 0) * HW + y) * HW + x;
    int o1 = o0 + HW * HW;
    out[o0] = acc0 + flow[o0];
    out[o1] = acc1 + flow[o1];
}

// ---------------- launch
extern "C" void kernel_launch(void* const* d_in, const int* in_sizes, int n_in,
                              void* d_out, int out_size, void* d_ws, size_t ws_size,
                              hipStream_t stream) {
    const float* ffirst  = (const float*)d_in[2];
    const float* fsecond = (const float*)d_in[3];
    const float* tflow   = (const float*)d_in[4];
    const float* wu      = (const float*)d_in[5];
    const float* w1 = (const float*)d_in[6];
    const float* b1 = (const float*)d_in[7];
    const float* w2 = (const float*)d_in[8];
    const float* b2 = (const float*)d_in[9];
    const float* w3 = (const float*)d_in[10];
    const float* b3 = (const float*)d_in[11];
    const float* w4 = (const float*)d_in[12];
    const float* b4 = (const float*)d_in[13];
    float* out = (float*)d_out;
    char* ws = (char*)d_ws;

    // packed weights
    u16* w1p = (u16*)(ws + 0);         // 147456 B
    u16* w2p = (u16*)(ws + 147456);    // 147456 B
    u16* w3p = (u16*)(ws + 294912);    // 36864 B
    float* w4p = (float*)(ws + 331776);// 6400 B

    float* flow = (float*)(ws + 602112);   // 2097152 B, ends 2699264
    u16* regA = (u16*)(ws + 2699264);      // feat2 NHWC 59.3MB -> x1p 69.2MB -> x3p 17.8MB
    u16* regB = (u16*)(ws + 71921664);     // corr 34.6MB -> x2p 34.6MB; end 106532864

    // 1) weight packing
    pack_w<49, 64, 128><<<288, 256, 0, stream>>>(w1, w1p);
    pack_w<128, 128, 64><<<288, 256, 0, stream>>>(w2, w2p);
    pack_w<64, 64, 32><<<72, 256, 0, stream>>>(w3, w3p);
    pack_w4<<<7, 256, 0, stream>>>(w4, w4p);

    // 2) upflow -> flow (f32 NCHW)
    upflow_kernel<<<2048, 256, 0, stream>>>(tflow, wu, flow);

    // 3) warp -> feat2 NHWC (16,134,144,96) bf16, pad-3 + x-pad
    hipMemsetAsync(regA, 0, 59277312, stream);
    warp_kernel<<<1024, 256, 0, stream>>>(fsecond, flow, regA);

    // 4) correlation (banded MFMA) + lrelu -> corr NHWC (130,130,64) bf16
    hipMemsetAsync(regB, 0, 34611200, stream);
    corr_mfma<<<4096, 256, 0, stream>>>(ffirst, regA, regB);

    // 5) conv1 64->128 MFMA -> x1p NHWC pad1 (feat2 dead)
    hipMemsetAsync(regA, 0, 69222400, stream);
    conv_mfma<64, 128, 64, 1><<<2048, 256, 0, stream>>>(regB, w1p, b1, regA);

    // 6) conv2 128->64 MFMA -> x2p NHWC pad1 (corr dead)
    hipMemsetAsync(regB, 0, 34611200, stream);
    conv_mfma<128, 64, 64, 1><<<1024, 256, 0, stream>>>(regA, w2p, b2, regB);

    // 7) conv3 64->32 MFMA -> x3p NHWC pad2 (x1 dead)
    hipMemsetAsync(regA, 0, 17842176, stream);
    conv_mfma<64, 32, 32, 2><<<1024, 256, 0, stream>>>(regB, w3p, b3, regA);

    // 8) conv4 5x5 32->2 + flow add -> d_out (f32 NCHW)
    conv4_kernel<<<1024, 256, 0, stream>>>(regA, w4p, b4, flow, out);
}

// Round 5
// 673.438 us; speedup vs baseline: 2.6285x; 1.1353x over previous
//
#include <hip/hip_runtime.h>

typedef unsigned short u16;
typedef unsigned int u32;
typedef short short8 __attribute__((ext_vector_type(8)));
typedef float f32x4 __attribute__((ext_vector_type(4)));

#define HW 128

__device__ __forceinline__ float bf2f(u16 h) {
    u32 u = ((u32)h) << 16;
    return __uint_as_float(u);
}
__device__ __forceinline__ u16 f2bf(float f) {
    u32 u = __float_as_uint(f);
    u32 r = (u + 0x7FFFu + ((u >> 16) & 1u)) >> 16;
    return (u16)r;
}
__device__ __forceinline__ float lrelu_f(float v) {
    return v >= 0.f ? v : 0.1f * v;
}

// ---------------- weight pack for MFMA convs: [oc][ic][3][3] f32 -> [tap][ch][quad][oc][j8] bf16
template<int ICR, int ICP, int OC>
__global__ __launch_bounds__(256) void pack_w(const float* __restrict__ w, u16* __restrict__ dst) {
    constexpr int NCH = ICP / 32;
    constexpr int NTOT = 9 * NCH * 4 * OC * 8;
    int gid = blockIdx.x * 256 + threadIdx.x;
    if (gid >= NTOT) return;
    int j = gid & 7;
    int t = gid >> 3;
    int oc = t % OC; t /= OC;
    int quad = t & 3; t >>= 2;
    int ch = t % NCH;
    int tap = t / NCH;
    int ic = ch * 32 + quad * 8 + j;
    int ky = tap / 3, kx = tap % 3;
    float v = (ic < ICR) ? w[((oc * ICR + ic) * 3 + ky) * 3 + kx] : 0.f;
    dst[gid] = f2bf(v);
}

// ---------------- conv4 weight pack: [2][32][5][5] f32 -> [tap(25)][oc(2)][ic(32)] f32
__global__ __launch_bounds__(256) void pack_w4(const float* __restrict__ w, float* __restrict__ dst) {
    int gid = blockIdx.x * 256 + threadIdx.x;
    if (gid >= 1600) return;
    int ic = gid & 31;
    int t = gid >> 5;
    int oc = t & 1;
    int tap = t >> 1;
    dst[(tap * 2 + oc) * 32 + ic] = w[(oc * 32 + ic) * 25 + tap];
}

// ---------------- upflow: transposed conv, lhs_dilation=2, pad=2, k=4, groups=2
__global__ __launch_bounds__(256) void upflow_kernel(const float* __restrict__ tflow, const float* __restrict__ wu,
                                                     float* __restrict__ flow) {
    int gid = blockIdx.x * 256 + threadIdx.x;   // 524288 exact
    int x = gid & 127;
    int y = (gid >> 7) & 127;
    int c = (gid >> 14) & 1;
    int b = gid >> 15;
    float acc = 0.f;
#pragma unroll
    for (int ky = 0; ky < 4; ++ky) {
        int u = y + ky - 2;
        if ((u & 1) || u < 0 || u > 126) continue;
        int iy = u >> 1;
#pragma unroll
        for (int kx = 0; kx < 4; ++kx) {
            int v = x + kx - 2;
            if ((v & 1) || v < 0 || v > 126) continue;
            int ix = v >> 1;
            acc += tflow[((b * 2 + c) * 64 + iy) * 64 + ix] *
                   wu[c * 16 + (3 - ky) * 4 + (3 - kx)];
        }
    }
    flow[gid] = acc;
}

// ---------------- backward warp -> fragment-native bf16 feat2 [b][row 134][cg 12][x 144][8]
// cg = ch*4+quad, channel = cg*8+j. Interior rows/cols only (halo pre-zeroed).
__global__ __launch_bounds__(256) void warp_kernel(const float* __restrict__ second, const float* __restrict__ flow,
                                                   u16* __restrict__ feat2) {
    int tid = threadIdx.x;
    int x = tid & 127;
    int half = tid >> 7;            // 0..1
    int blk = blockIdx.x;           // (b*128 + y)*6 + cgp
    int cgp = blk % 6;
    int t = blk / 6;
    int y = t & 127;
    int b = t >> 7;
    int cg = cgp * 2 + half;        // 0..11

    float fx = (float)x + 2.5f * flow[((b * 2 + 0) * HW + y) * HW + x];
    float fy = (float)y + 2.5f * flow[((b * 2 + 1) * HW + y) * HW + x];
    float x0f = floorf(fx), y0f = floorf(fy);
    int x0 = (int)x0f, y0 = (int)y0f;
    int x1 = x0 + 1, y1 = y0 + 1;
    float wx1 = fx - x0f, wx0 = (x0f + 1.f) - fx;
    float wy1 = fy - y0f, wy0 = (y0f + 1.f) - fy;
    float wA = wx0 * wy0, wB = wx1 * wy0, wC = wx0 * wy1, wD = wx1 * wy1;
    float vA = (x0 >= 0 && x0 <= 127 && y0 >= 0 && y0 <= 127) ? 1.f : 0.f;
    float vB = (x1 >= 0 && x1 <= 127 && y0 >= 0 && y0 <= 127) ? 1.f : 0.f;
    float vC = (x0 >= 0 && x0 <= 127 && y1 >= 0 && y1 <= 127) ? 1.f : 0.f;
    float vD = (x1 >= 0 && x1 <= 127 && y1 >= 0 && y1 <= 127) ? 1.f : 0.f;
    wA *= vA; wB *= vB; wC *= vC; wD *= vD;
    float ones = wA + wB + wC + wD;
    float maskf = (ones > 0.999f) ? 1.f : 0.f;
    wA *= maskf; wB *= maskf; wC *= maskf; wD *= maskf;
    int xc0 = min(max(x0, 0), 127), xc1 = min(max(x1, 0), 127);
    int yc0 = min(max(y0, 0), 127), yc1 = min(max(y1, 0), 127);
    int i00 = yc0 * HW + xc0, i01 = yc0 * HW + xc1;
    int i10 = yc1 * HW + xc0, i11 = yc1 * HW + xc1;

    const float* base = second + (size_t)b * 96 * HW * HW + (size_t)(cg * 8) * (HW * HW);
    short8 o;
#pragma unroll
    for (int j = 0; j < 8; ++j) {
        const float* pp = base + (size_t)j * (HW * HW);
        float v = wA * pp[i00] + wB * pp[i01] + wC * pp[i10] + wD * pp[i11];
        o[j] = (short)f2bf(v);
    }
    *(short8*)(feat2 + ((((size_t)(b * 134) + y + 3) * 12 + cg) * 144 + (x + 3)) * 8) = o;
}

// ---------------- correlation as banded MFMA GEMM -> NHWC (16,130,130,64) bf16 corr, + /96 + lrelu
// A from fp32 NCHW first; B from fragment-native feat2 (coalesced 16B/lane loads)
__global__ __launch_bounds__(256) void corr_mfma(const float* __restrict__ first, const u16* __restrict__ feat2,
                                                 u16* __restrict__ corrp) {
    int tid = threadIdx.x;
    int wave = tid >> 6, lane = tid & 63;
    int quad = lane >> 4, l16 = lane & 15;
    int blk = blockIdx.x;            // 16 * 128 * 2 = 4096
    int half = blk & 1;
    int y = (blk >> 1) & 127;
    int b = blk >> 8;
    int x0 = (half * 4 + wave) * 16;

    // A fragments: lane m=l16 -> pixel x0+l16, k = ch*32 + quad*8 + j
    short8 afr[3];
    const float* fbase = first + ((size_t)(b * 96) * HW + y) * HW + x0 + l16;
#pragma unroll
    for (int ch = 0; ch < 3; ++ch) {
        short8 a;
#pragma unroll
        for (int j = 0; j < 8; ++j)
            a[j] = (short)f2bf(fbase[(size_t)(ch * 32 + quad * 8 + j) * (HW * HW)]);
        afr[ch] = a;
    }

    f32x4 acc[7][2];
#pragma unroll
    for (int dy = 0; dy < 7; ++dy) {
        acc[dy][0] = (f32x4){0.f, 0.f, 0.f, 0.f};
        acc[dy][1] = (f32x4){0.f, 0.f, 0.f, 0.f};
    }

#pragma unroll
    for (int dy = 0; dy < 7; ++dy) {
#pragma unroll
        for (int ch = 0; ch < 3; ++ch) {
            // feat2 [b][row y+dy][cg=ch*4+quad][x][8]; B col n = x0+l16 (+16 for tile 1)
            const u16* rp = feat2 + ((((size_t)(b * 134) + y + dy) * 12 + ch * 4 + quad) * 144 + x0 + l16) * 8;
            short8 b0 = *(const short8*)(rp);
            short8 b1 = *(const short8*)(rp + 16 * 8);
            acc[dy][0] = __builtin_amdgcn_mfma_f32_16x16x32_bf16(afr[ch], b0, acc[dy][0], 0, 0, 0);
            acc[dy][1] = __builtin_amdgcn_mfma_f32_16x16x32_bf16(afr[ch], b1, acc[dy][1], 0, 0, 0);
        }
    }

    // band extract: lane holds col n=l16 (within tile), rows m=quad*4+r; dx = nt*16+l16-m
    u16* op = corrp + ((size_t)(b * 130) + y + 1) * (130 * 64);
#pragma unroll
    for (int dy = 0; dy < 7; ++dy)
#pragma unroll
        for (int nt = 0; nt < 2; ++nt)
#pragma unroll
            for (int r = 0; r < 4; ++r) {
                int m = quad * 4 + r;
                int dx = nt * 16 + l16 - m;
                if (dx >= 0 && dx < 7) {
                    float v = lrelu_f(acc[dy][nt][r] * (1.f / 96.f));
                    op[(size_t)(x0 + m + 1) * 64 + dy * 7 + dx] = f2bf(v);
                }
            }
}

// ---------------- MFMA conv 3x3: NHWC pad-1 in (130x130xICP) -> NHWC pad-PADOUT out, + bias + lrelu
template<int ICP, int OC, int OCB, int PADOUT>
__global__ __launch_bounds__(256) void conv_mfma(const u16* __restrict__ in, const u16* __restrict__ wp,
                                                 const float* __restrict__ bias, u16* __restrict__ out) {
    constexpr int NCH = ICP / 32;
    constexpr int NOCT = OCB / 16;
    constexpr int OCG = OC / OCB;
    constexpr int Wi = 130;
    constexpr int Wo = 128 + 2 * PADOUT;
    int tid = threadIdx.x;
    int wave = tid >> 6, lane = tid & 63;
    int quad = lane >> 4, l16 = lane & 15;
    int rowpair = blockIdx.x & 63;
    int t = blockIdx.x >> 6;
    int ocg = t % OCG;
    int b = t / OCG;
    int row = rowpair * 2 + (wave >> 1);
    int px0 = (wave & 1) * 64;

    f32x4 acc[4][NOCT];
#pragma unroll
    for (int mt = 0; mt < 4; ++mt)
#pragma unroll
        for (int ot = 0; ot < NOCT; ++ot)
            acc[mt][ot] = (f32x4){0.f, 0.f, 0.f, 0.f};

#pragma unroll
    for (int ky = 0; ky < 3; ++ky) {
#pragma unroll
        for (int kx = 0; kx < 3; ++kx) {
#pragma unroll
            for (int ch = 0; ch < NCH; ++ch) {
                const u16* aptr = in + ((size_t)(b * Wi + row + ky) * Wi + px0 + kx + l16) * ICP + ch * 32 + quad * 8;
                short8 afr[4];
#pragma unroll
                for (int mt = 0; mt < 4; ++mt)
                    afr[mt] = *(const short8*)(aptr + mt * 16 * ICP);
                const u16* bptr = wp + ((((size_t)(ky * 3 + kx) * NCH + ch) * 4 + quad) * OC + ocg * OCB + l16) * 8;
                short8 bfr[NOCT];
#pragma unroll
                for (int ot = 0; ot < NOCT; ++ot)
                    bfr[ot] = *(const short8*)(bptr + ot * 16 * 8);
#pragma unroll
                for (int mt = 0; mt < 4; ++mt)
#pragma unroll
                    for (int ot = 0; ot < NOCT; ++ot)
                        acc[mt][ot] = __builtin_amdgcn_mfma_f32_16x16x32_bf16(afr[mt], bfr[ot], acc[mt][ot], 0, 0, 0);
            }
        }
    }

    float bv[NOCT];
#pragma unroll
    for (int ot = 0; ot < NOCT; ++ot) bv[ot] = bias[ocg * OCB + ot * 16 + l16];

#pragma unroll
    for (int mt = 0; mt < 4; ++mt) {
#pragma unroll
        for (int ot = 0; ot < NOCT; ++ot) {
#pragma unroll
            for (int r = 0; r < 4; ++r) {
                int px = px0 + mt * 16 + quad * 4 + r;
                float v = lrelu_f(acc[mt][ot][r] + bv[ot]);
                out[((size_t)(b * Wo + row + PADOUT) * Wo + px + PADOUT) * OC + ocg * OCB + ot * 16 + l16] = f2bf(v);
            }
        }
    }
}

// ---------------- conv4: 5x5, 32->2, NHWC pad-2 in (132x132x32), + flow add -> NCHW f32 out
__global__ __launch_bounds__(256) void conv4_kernel(const u16* __restrict__ in, const float* __restrict__ w4p,
                                                    const float* __restrict__ b4, const float* __restrict__ flow,
                                                    float* __restrict__ out) {
    int gid = blockIdx.x * 256 + threadIdx.x;   // 16*128*128
    int x = gid & 127;
    int y = (gid >> 7) & 127;
    int b = gid >> 14;
    float acc0 = b4[0], acc1 = b4[1];
#pragma unroll
    for (int ky = 0; ky < 5; ++ky) {
#pragma unroll
        for (int kx = 0; kx < 5; ++kx) {
            const u16* p = in + ((size_t)(b * 132 + y + ky) * 132 + x + kx) * 32;
            const float* wb = w4p + (ky * 5 + kx) * 64;
#pragma unroll
            for (int g = 0; g < 4; ++g) {
                short8 vv = *(const short8*)(p + g * 8);
#pragma unroll
                for (int j = 0; j < 8; ++j) {
                    float v = bf2f((u16)vv[j]);
                    acc0 += v * wb[g * 8 + j];
                    acc1 += v * wb[32 + g * 8 + j];
                }
            }
        }
    }
    int o0 = ((b * 2 + 0) * HW + y) * HW + x;
    int o1 = o0 + HW * HW;
    out[o0] = acc0 + flow[o0];
    out[o1] = acc1 + flow[o1];
}

// ---------------- launch
extern "C" void kernel_launch(void* const* d_in, const int* in_sizes, int n_in,
                              void* d_out, int out_size, void* d_ws, size_t ws_size,
                              hipStream_t stream) {
    const float* ffirst  = (const float*)d_in[2];
    const float* fsecond = (const float*)d_in[3];
    const float* tflow   = (const float*)d_in[4];
    const float* wu      = (const float*)d_in[5];
    const float* w1 = (const float*)d_in[6];
    const float* b1 = (const float*)d_in[7];
    const float* w2 = (const float*)d_in[8];
    const float* b2 = (const float*)d_in[9];
    const float* w3 = (const float*)d_in[10];
    const float* b3 = (const float*)d_in[11];
    const float* w4 = (const float*)d_in[12];
    const float* b4 = (const float*)d_in[13];
    float* out = (float*)d_out;
    char* ws = (char*)d_ws;

    // packed weights
    u16* w1p = (u16*)(ws + 0);         // 147456 B
    u16* w2p = (u16*)(ws + 147456);    // 147456 B
    u16* w3p = (u16*)(ws + 294912);    // 36864 B
    float* w4p = (float*)(ws + 331776);// 6400 B

    float* flow = (float*)(ws + 602112);   // 2097152 B, ends 2699264
    u16* regA = (u16*)(ws + 2699264);      // feat2 59.3MB -> x1p 69.2MB -> x3p 17.8MB
    u16* regB = (u16*)(ws + 71921664);     // corr 34.6MB -> x2p 34.6MB; end 106532864

    // 1) weight packing
    pack_w<49, 64, 128><<<288, 256, 0, stream>>>(w1, w1p);
    pack_w<128, 128, 64><<<288, 256, 0, stream>>>(w2, w2p);
    pack_w<64, 64, 32><<<72, 256, 0, stream>>>(w3, w3p);
    pack_w4<<<7, 256, 0, stream>>>(w4, w4p);

    // 2) upflow -> flow (f32 NCHW)
    upflow_kernel<<<2048, 256, 0, stream>>>(tflow, wu, flow);

    // 3) warp -> feat2 fragment-native [16][134][12][144][8] bf16
    hipMemsetAsync(regA, 0, 59277312, stream);
    warp_kernel<<<12288, 256, 0, stream>>>(fsecond, flow, regA);

    // 4) correlation (banded MFMA) + lrelu -> corr NHWC (130,130,64) bf16
    hipMemsetAsync(regB, 0, 34611200, stream);
    corr_mfma<<<4096, 256, 0, stream>>>(ffirst, regA, regB);

    // 5) conv1 64->128 MFMA -> x1p NHWC pad1 (feat2 dead)
    hipMemsetAsync(regA, 0, 69222400, stream);
    conv_mfma<64, 128, 64, 1><<<2048, 256, 0, stream>>>(regB, w1p, b1, regA);

    // 6) conv2 128->64 MFMA -> x2p NHWC pad1 (corr dead)
    hipMemsetAsync(regB, 0, 34611200, stream);
    conv_mfma<128, 64, 64, 1><<<1024, 256, 0, stream>>>(regA, w2p, b2, regB);

    // 7) conv3 64->32 MFMA -> x3p NHWC pad2 (x1 dead)
    hipMemsetAsync(regA, 0, 17842176, stream);
    conv_mfma<64, 32, 32, 2><<<1024, 256, 0, stream>>>(regB, w3p, b3, regA);

    // 8) conv4 5x5 32->2 + flow add -> d_out (f32 NCHW)
    conv4_kernel<<<1024, 256, 0, stream>>>(regA, w4p, b4, flow, out);
}